// Round 1
// baseline (1191.593 us; speedup 1.0000x reference)
//
#include <hip/hip_runtime.h>

// GCN 2-layer forward on MI355X.
// N=150000 nodes, E=1.2M edges, IN=HID=64, layer2 out dim = 1.
//
// Math refactor (per layer):  pre = dinv[v] * ( sum_{e:dst=v} Y[src] + Y[v] ) + b
// where Y = (x @ W) * dinv[v]  (row-scaled).  Self-loop term is folded into the
// accumulator initialization (AGG := Y), so no big memset is needed.

__global__ __launch_bounds__(256) void k_deg(const int* __restrict__ dst, int E, int* __restrict__ deg) {
    int e = blockIdx.x * 256 + threadIdx.x;
    if (e < E) atomicAdd(&deg[dst[e]], 1);
}

__global__ __launch_bounds__(256) void k_dinv(const int* __restrict__ deg, int N, float* __restrict__ dinv) {
    int v = blockIdx.x * 256 + threadIdx.x;
    if (v < N) dinv[v] = rsqrtf((float)deg[v] + 1.0f);
}

// X[N,64] @ W[64,64], row-scale by dinv, write Y and AGG(=self-loop init).
// Block = 256 threads handles 64 rows. W and A-tile staged in LDS.
__global__ __launch_bounds__(256) void k_gemm1(const float* __restrict__ X, const float* __restrict__ W,
                                               const float* __restrict__ dinv, int N,
                                               float* __restrict__ Y, float* __restrict__ AGG) {
    __shared__ float Wl[64 * 64];
    __shared__ float Al[64 * 66];   // pad 66: (66r+k)%32 = (2r+k)%32 -> 2-way (free)
    const int t = threadIdx.x;
    const int row0 = blockIdx.x * 64;

    // stage W (4096 floats) via float4
    {
        const float4* Wv = (const float4*)W;
        float4* Wlv = (float4*)Wl;
#pragma unroll
        for (int i = 0; i < 4; i++) Wlv[t + i * 256] = Wv[t + i * 256];
    }
    // stage A tile (64 rows x 64 floats), coalesced float4 global reads
    {
#pragma unroll
        for (int i = 0; i < 4; i++) {
            int f = t + i * 256;       // float4 index 0..1023
            int r = f >> 4;
            int c4 = f & 15;
            int gr = row0 + r;
            float4 v = (gr < N) ? ((const float4*)X)[gr * 16 + c4] : make_float4(0.f, 0.f, 0.f, 0.f);
            float* dp = &Al[r * 66 + c4 * 4];
            dp[0] = v.x; dp[1] = v.y; dp[2] = v.z; dp[3] = v.w;
        }
    }
    __syncthreads();

    const int r = t & 63;      // row within tile (lane id -> 2-way LDS, free)
    const int cb = t >> 6;     // column block 0..3 (wave-uniform -> W reads broadcast)
    float acc[16];
#pragma unroll
    for (int j = 0; j < 16; j++) acc[j] = 0.f;
#pragma unroll 8
    for (int k = 0; k < 64; k++) {
        float a = Al[r * 66 + k];
#pragma unroll
        for (int j = 0; j < 16; j++)
            acc[j] = fmaf(a, Wl[k * 64 + cb * 16 + j], acc[j]);
    }
    int gr = row0 + r;
    if (gr < N) {
        float s = dinv[gr];
#pragma unroll
        for (int j = 0; j < 16; j += 4) {
            float4 o = make_float4(acc[j] * s, acc[j + 1] * s, acc[j + 2] * s, acc[j + 3] * s);
            ((float4*)(Y + gr * 64 + cb * 16))[j >> 2] = o;
            ((float4*)(AGG + gr * 64 + cb * 16))[j >> 2] = o;
        }
    }
}

// Edge scatter: AGG[dst] += Y[src].  16 lanes per edge, float4 gather + 4 atomics/lane.
__global__ __launch_bounds__(256) void k_scatter(const int* __restrict__ src, const int* __restrict__ dst,
                                                 const float* __restrict__ Y, int E,
                                                 float* __restrict__ AGG) {
    int t = blockIdx.x * 256 + threadIdx.x;
    int e = t >> 4;
    if (e >= E) return;
    int li = t & 15;
    int s = src[e];
    int d = dst[e];
    float4 v = ((const float4*)(Y + (size_t)s * 64))[li];
    float* ap = AGG + (size_t)d * 64 + li * 4;
    atomicAdd(ap + 0, v.x);
    atomicAdd(ap + 1, v.y);
    atomicAdd(ap + 2, v.z);
    atomicAdd(ap + 3, v.w);
}

// h1 = relu(dinv*AGG + b1); z = h1 . W2; zs = z * dinv.   16 lanes per node.
__global__ __launch_bounds__(256) void k_h1z(const float* __restrict__ AGG, const float* __restrict__ b1,
                                             const float* __restrict__ W2, const float* __restrict__ dinv,
                                             int N, float* __restrict__ zs) {
    int t = blockIdx.x * 256 + threadIdx.x;
    int v = t >> 4;
    if (v >= N) return;
    int li = t & 15;
    float dv = dinv[v];
    float4 a = ((const float4*)(AGG + (size_t)v * 64))[li];
    float4 bb = ((const float4*)b1)[li];
    float4 w = ((const float4*)W2)[li];
    float h0 = fmaxf(fmaf(dv, a.x, bb.x), 0.f);
    float h1 = fmaxf(fmaf(dv, a.y, bb.y), 0.f);
    float h2 = fmaxf(fmaf(dv, a.z, bb.z), 0.f);
    float h3 = fmaxf(fmaf(dv, a.w, bb.w), 0.f);
    float p = h0 * w.x + h1 * w.y + h2 * w.z + h3 * w.w;
    p += __shfl_xor(p, 1);
    p += __shfl_xor(p, 2);
    p += __shfl_xor(p, 4);
    p += __shfl_xor(p, 8);
    if (li == 0) zs[v] = p * dv;
}

__global__ __launch_bounds__(256) void k_scatter2(const int* __restrict__ src, const int* __restrict__ dst,
                                                  const float* __restrict__ zs, int E,
                                                  float* __restrict__ aggz) {
    int e = blockIdx.x * 256 + threadIdx.x;
    if (e < E) atomicAdd(&aggz[dst[e]], zs[src[e]]);
}

// out[i] = relu(dinv[v]*(aggz[v]+zs[v]) + b2), v = (i/12)*15 + 3 + i%12
__global__ __launch_bounds__(256) void k_out(const float* __restrict__ aggz, const float* __restrict__ zs,
                                             const float* __restrict__ dinv, const float* __restrict__ b2,
                                             int M, float* __restrict__ out) {
    int i = blockIdx.x * 256 + threadIdx.x;
    if (i >= M) return;
    int q = i / 12;
    int c = i - q * 12;
    int v = q * 15 + 3 + c;
    float tv = fmaf(dinv[v], aggz[v] + zs[v], b2[0]);
    out[i] = fmaxf(tv, 0.f);
}

extern "C" void kernel_launch(void* const* d_in, const int* in_sizes, int n_in,
                              void* d_out, int out_size, void* d_ws, size_t ws_size,
                              hipStream_t stream) {
    const float* obs = (const float*)d_in[0];
    const int*   ei  = (const int*)d_in[1];   // [2,E] row-major; JAX x64-off -> int32
    const float* W1  = (const float*)d_in[2];
    const float* b1  = (const float*)d_in[3];
    const float* W2  = (const float*)d_in[4];
    const float* b2  = (const float*)d_in[5];

    const int N = in_sizes[0] / 64;
    const int E = in_sizes[1] / 2;
    const int M = out_size;

    const int* src = ei;
    const int* dst = ei + E;

    // workspace layout (floats)
    float* Y    = (float*)d_ws;          // N*64
    float* AGG  = Y + (size_t)N * 64;    // N*64
    float* dinv = AGG + (size_t)N * 64;  // N
    float* zs   = dinv + N;              // N
    float* aggz = zs + N;                // N
    int*   deg  = (int*)(aggz + N);      // N
    // total = 132*N floats = ~79.2 MB

    // zero aggz + deg (contiguous, 2*N*4 bytes)
    hipMemsetAsync(aggz, 0, (size_t)2 * N * sizeof(float), stream);

    k_deg<<<(E + 255) / 256, 256, 0, stream>>>(dst, E, deg);
    k_dinv<<<(N + 255) / 256, 256, 0, stream>>>(deg, N, dinv);
    k_gemm1<<<(N + 63) / 64, 256, 0, stream>>>(obs, W1, dinv, N, Y, AGG);
    k_scatter<<<(E * 16 + 255) / 256, 256, 0, stream>>>(src, dst, Y, E, AGG);
    k_h1z<<<(N * 16 + 255) / 256, 256, 0, stream>>>(AGG, b1, W2, dinv, N, zs);
    k_scatter2<<<(E + 255) / 256, 256, 0, stream>>>(src, dst, zs, E, aggz);
    k_out<<<(M + 255) / 256, 256, 0, stream>>>(aggz, zs, dinv, b2, M, (float*)d_out);
}

// Round 2
// 257.059 us; speedup vs baseline: 4.6355x; 4.6355x over previous
//
#include <hip/hip_runtime.h>

// GCN 2-layer forward on MI355X — CSR-gather formulation (no fp32 atomics).
// N=150000, E=1.2M, IN=HID=64, layer-2 out dim = 1.
//
// Math:  pre1 = dinv[v]*(sum_{e:dst=v} Y[src] + Y[v]) + b1,  Y = (x@W1)*dinv row-scaled
//        z    = relu(pre1) . W2 ; zs = z*dinv
//        out  = relu(dinv[v]*(sum zs[src] + zs[v]) + b2)   sliced v%15 in 3..14

__global__ __launch_bounds__(256) void k_deg(const int* __restrict__ dst, int E, int* __restrict__ deg) {
    int e = blockIdx.x * 256 + threadIdx.x;
    if (e < E) atomicAdd(&deg[dst[e]], 1);
}

__global__ __launch_bounds__(256) void k_dinv(const int* __restrict__ deg, int N, float* __restrict__ dinv) {
    int v = blockIdx.x * 256 + threadIdx.x;
    if (v < N) dinv[v] = rsqrtf((float)deg[v] + 1.0f);
}

// ---- 3-pass exclusive scan of deg[N] -> rowptr[N] (+ cursor copy) ----
__global__ __launch_bounds__(256) void k_scan1(const int* __restrict__ deg, int N, int* __restrict__ bsum) {
    __shared__ int s[256];
    int i = blockIdx.x * 256 + threadIdx.x;
    s[threadIdx.x] = (i < N) ? deg[i] : 0;
    __syncthreads();
    for (int o = 128; o > 0; o >>= 1) {
        if (threadIdx.x < o) s[threadIdx.x] += s[threadIdx.x + o];
        __syncthreads();
    }
    if (threadIdx.x == 0) bsum[blockIdx.x] = s[0];
}

__global__ __launch_bounds__(1024) void k_scan2(const int* __restrict__ bsum, int nb, int* __restrict__ boff) {
    __shared__ int s[1024];
    int t = threadIdx.x;
    int v = (t < nb) ? bsum[t] : 0;
    s[t] = v;
    __syncthreads();
    for (int o = 1; o < 1024; o <<= 1) {
        int x = s[t];
        if (t >= o) x += s[t - o];
        __syncthreads();
        s[t] = x;
        __syncthreads();
    }
    if (t < nb) boff[t] = s[t] - v;  // exclusive
}

__global__ __launch_bounds__(256) void k_scan3(const int* __restrict__ deg, const int* __restrict__ boff,
                                               int N, int* __restrict__ rowptr, int* __restrict__ cursor) {
    __shared__ int s[256];
    int i = blockIdx.x * 256 + threadIdx.x;
    int v = (i < N) ? deg[i] : 0;
    s[threadIdx.x] = v;
    __syncthreads();
    for (int o = 1; o < 256; o <<= 1) {
        int x = s[threadIdx.x];
        if (threadIdx.x >= o) x += s[threadIdx.x - o];
        __syncthreads();
        s[threadIdx.x] = x;
        __syncthreads();
    }
    if (i < N) {
        int ex = s[threadIdx.x] - v + boff[blockIdx.x];
        rowptr[i] = ex;
        cursor[i] = ex;
    }
}

__global__ __launch_bounds__(256) void k_fill(const int* __restrict__ src, const int* __restrict__ dst,
                                              int E, int* __restrict__ cursor, int* __restrict__ csrc) {
    int e = blockIdx.x * 256 + threadIdx.x;
    if (e < E) {
        int p = atomicAdd(&cursor[dst[e]], 1);
        csrc[p] = src[e];
    }
}

// X[N,64] @ W[64,64], row-scale by dinv -> Y.
__global__ __launch_bounds__(256) void k_gemm1(const float* __restrict__ X, const float* __restrict__ W,
                                               const float* __restrict__ dinv, int N,
                                               float* __restrict__ Y) {
    __shared__ float Wl[64 * 64];
    __shared__ float Al[64 * 66];
    const int t = threadIdx.x;
    const int row0 = blockIdx.x * 64;
    {
        const float4* Wv = (const float4*)W;
        float4* Wlv = (float4*)Wl;
#pragma unroll
        for (int i = 0; i < 4; i++) Wlv[t + i * 256] = Wv[t + i * 256];
    }
    {
#pragma unroll
        for (int i = 0; i < 4; i++) {
            int f = t + i * 256;
            int r = f >> 4;
            int c4 = f & 15;
            int gr = row0 + r;
            float4 v = (gr < N) ? ((const float4*)X)[gr * 16 + c4] : make_float4(0.f, 0.f, 0.f, 0.f);
            float* dp = &Al[r * 66 + c4 * 4];
            dp[0] = v.x; dp[1] = v.y; dp[2] = v.z; dp[3] = v.w;
        }
    }
    __syncthreads();

    const int r = t & 63;
    const int cb = t >> 6;
    float acc[16];
#pragma unroll
    for (int j = 0; j < 16; j++) acc[j] = 0.f;
#pragma unroll 8
    for (int k = 0; k < 64; k++) {
        float a = Al[r * 66 + k];
#pragma unroll
        for (int j = 0; j < 16; j++)
            acc[j] = fmaf(a, Wl[k * 64 + cb * 16 + j], acc[j]);
    }
    int gr = row0 + r;
    if (gr < N) {
        float s = dinv[gr];
#pragma unroll
        for (int j = 0; j < 16; j += 4)
            ((float4*)(Y + (size_t)gr * 64 + cb * 16))[j >> 2] =
                make_float4(acc[j] * s, acc[j + 1] * s, acc[j + 2] * s, acc[j + 3] * s);
    }
}

// Fused: layer-1 CSR gather + self-loop + bias/relu + dot(W2) + *dinv -> zs[v].
// 16 lanes per node; each lane owns 4 features (float4).
__global__ __launch_bounds__(256) void k_agg(const float* __restrict__ Y, const int* __restrict__ rowptr,
                                             const int* __restrict__ deg, const int* __restrict__ csrc,
                                             const float* __restrict__ dinv, const float* __restrict__ b1,
                                             const float* __restrict__ W2, int N, float* __restrict__ zs) {
    int t = blockIdx.x * 256 + threadIdx.x;
    int v = t >> 4;
    if (v >= N) return;
    int li = t & 15;
    int start = rowptr[v];
    int cnt = deg[v];
    float4 acc = ((const float4*)(Y + (size_t)v * 64))[li];  // self-loop term
    for (int j = 0; j < cnt; j++) {
        int s = csrc[start + j];                              // broadcast across 16 lanes
        float4 m = ((const float4*)(Y + (size_t)s * 64))[li]; // coalesced 256B row
        acc.x += m.x; acc.y += m.y; acc.z += m.z; acc.w += m.w;
    }
    float dv = dinv[v];
    float4 bb = ((const float4*)b1)[li];
    float4 w  = ((const float4*)W2)[li];
    float h0 = fmaxf(fmaf(dv, acc.x, bb.x), 0.f);
    float h1 = fmaxf(fmaf(dv, acc.y, bb.y), 0.f);
    float h2 = fmaxf(fmaf(dv, acc.z, bb.z), 0.f);
    float h3 = fmaxf(fmaf(dv, acc.w, bb.w), 0.f);
    float p = h0 * w.x + h1 * w.y + h2 * w.z + h3 * w.w;
    p += __shfl_xor(p, 1);
    p += __shfl_xor(p, 2);
    p += __shfl_xor(p, 4);
    p += __shfl_xor(p, 8);
    if (li == 0) zs[v] = p * dv;
}

// Fused layer-2 gather + output slice: out[i], v = (i/12)*15 + 3 + i%12.
__global__ __launch_bounds__(256) void k_out2(const float* __restrict__ zs, const int* __restrict__ rowptr,
                                              const int* __restrict__ deg, const int* __restrict__ csrc,
                                              const float* __restrict__ dinv, const float* __restrict__ b2,
                                              int M, float* __restrict__ out) {
    int i = blockIdx.x * 256 + threadIdx.x;
    if (i >= M) return;
    int q = i / 12;
    int c = i - q * 12;
    int v = q * 15 + 3 + c;
    int start = rowptr[v];
    int cnt = deg[v];
    float s = zs[v];
    for (int j = 0; j < cnt; j++) s += zs[csrc[start + j]];  // zs is 600KB -> L2 hits
    out[i] = fmaxf(fmaf(dinv[v], s, b2[0]), 0.f);
}

extern "C" void kernel_launch(void* const* d_in, const int* in_sizes, int n_in,
                              void* d_out, int out_size, void* d_ws, size_t ws_size,
                              hipStream_t stream) {
    const float* obs = (const float*)d_in[0];
    const int*   ei  = (const int*)d_in[1];   // [2,E]; JAX x64-off -> int32
    const float* W1  = (const float*)d_in[2];
    const float* b1  = (const float*)d_in[3];
    const float* W2  = (const float*)d_in[4];
    const float* b2  = (const float*)d_in[5];

    const int N = in_sizes[0] / 64;
    const int E = in_sizes[1] / 2;
    const int M = out_size;
    const int nb = (N + 255) / 256;          // 586 <= 1024

    const int* src = ei;
    const int* dst = ei + E;

    // workspace layout
    float* Y      = (float*)d_ws;             // N*64 floats (38.4 MB)
    float* dinv   = Y + (size_t)N * 64;       // N
    float* zs     = dinv + N;                 // N
    int*   deg    = (int*)(zs + N);           // N
    int*   rowptr = deg + N;                  // N
    int*   cursor = rowptr + N;               // N
    int*   bsum   = cursor + N;               // 1024
    int*   boff   = bsum + 1024;              // 1024
    int*   csrc   = boff + 1024;              // E  (4.8 MB)
    // total ~ 48 MB

    hipMemsetAsync(deg, 0, (size_t)N * sizeof(int), stream);

    k_deg  <<<(E + 255) / 256, 256, 0, stream>>>(dst, E, deg);
    k_dinv <<<(N + 255) / 256, 256, 0, stream>>>(deg, N, dinv);
    k_scan1<<<nb, 256, 0, stream>>>(deg, N, bsum);
    k_scan2<<<1, 1024, 0, stream>>>(bsum, nb, boff);
    k_scan3<<<nb, 256, 0, stream>>>(deg, boff, N, rowptr, cursor);
    k_fill <<<(E + 255) / 256, 256, 0, stream>>>(src, dst, E, cursor, csrc);
    k_gemm1<<<(N + 63) / 64, 256, 0, stream>>>(obs, W1, dinv, N, Y);
    k_agg  <<<((size_t)N * 16 + 255) / 256, 256, 0, stream>>>(Y, rowptr, deg, csrc, dinv, b1, W2, N, zs);
    k_out2 <<<(M + 255) / 256, 256, 0, stream>>>(zs, rowptr, deg, csrc, dinv, b2, M, (float*)d_out);
}